// Round 1
// baseline (190.561 us; speedup 1.0000x reference)
//
#include <hip/hip_runtime.h>

#define HW 512
#define NSTATE (HW * HW)          // 262144
#define NC4_1 196608              // 786432/4  (3*H*W floats as float4)
#define NC4_P 262144              // 1048576/4 (4*H*W floats as float4)
#define GRID_MV 1024
#define CHUNK1 (NC4_1 / GRID_MV)  // 192
#define CHUNKP (NC4_P / GRID_MV)  // 256

// ws layout (float offsets)
#define WS_PART1 0
#define WS_H2 (32 * GRID_MV)          // 32768
#define WS_P (WS_H2 + 64)             // 32832
#define WS_RD (WS_P + NSTATE)         // 294976
#define WS_V (WS_RD + NSTATE)         // 557120
#define WS_PART2 (WS_V + NSTATE)      // 819264
// total floats = 819264 + 32768 = 852032  (~3.4 MB)

// ---------------------------------------------------------------------------
// 32-row matvec: partials[block][row] = sum over block's column chunk.
// Input vector is segA (lenA4 float4s) followed by segB.
// 4 waves/block, 8 rows/wave; lanes stride the chunk; wave shuffle-reduce.
// ---------------------------------------------------------------------------
__global__ __launch_bounds__(256) void matvec32_partials(
    const float4* __restrict__ W4, const float4* __restrict__ A4, int lenA4,
    const float4* __restrict__ B4, int ncols4, int chunk4,
    float* __restrict__ partials) {
  int tid = threadIdx.x;
  int wave = tid >> 6, lane = tid & 63;
  int c0 = blockIdx.x * chunk4;
  for (int r = 0; r < 8; ++r) {
    int row = wave * 8 + r;
    const float4* Wrow = W4 + (size_t)row * ncols4;
    float acc = 0.f;
    for (int c = c0 + lane; c < c0 + chunk4; c += 64) {
      float4 w = Wrow[c];
      float4 x = (c < lenA4) ? A4[c] : B4[c - lenA4];
      acc += w.x * x.x + w.y * x.y + w.z * x.z + w.w * x.w;
    }
    for (int off = 32; off; off >>= 1) acc += __shfl_down(acc, off);
    if (lane == 0) partials[blockIdx.x * 32 + row] = acc;
  }
}

// ---------------------------------------------------------------------------
// Reduce partials -> h1 = relu(W1@state+b1); h2 = relu(W2@h1+b2). One block.
// ---------------------------------------------------------------------------
__global__ __launch_bounds__(256) void finish_h(
    const float* __restrict__ partials, const float* __restrict__ b1,
    const float* __restrict__ W2, const float* __restrict__ b2,
    float* __restrict__ h2out) {
  __shared__ float red[8][32];
  __shared__ float h1[32];
  int tid = threadIdx.x;
  int row = tid & 31, grp = tid >> 5;
  float s = 0.f;
  for (int b = grp; b < GRID_MV; b += 8) s += partials[b * 32 + row];
  red[grp][row] = s;
  __syncthreads();
  if (tid < 32) {
    float t = b1[tid];
    for (int g = 0; g < 8; ++g) t += red[g][tid];
    h1[tid] = fmaxf(t, 0.f);
  }
  __syncthreads();
  if (tid < 64) {
    float t = b2[tid];
    for (int k = 0; k < 32; ++k) t += W2[tid * 32 + k] * h1[k];
    h2out[tid] = fmaxf(t, 0.f);
  }
}

// ---------------------------------------------------------------------------
// Fused r_out/r_in/p kernel: for each of 262144 outputs, 3 dots of length 64
// against h2, sigmoids; store p and rd = sig(ri) - sig(ro).
// Quarter-wave (16 lanes) per output; 4 outputs per wave step; each wave
// instruction reads 1 KB contiguous from each weight matrix.
// ---------------------------------------------------------------------------
__global__ __launch_bounds__(256) void rop_kernel(
    const float4* __restrict__ Wro4, const float* __restrict__ bro,
    const float4* __restrict__ Wri4, const float* __restrict__ bri,
    const float4* __restrict__ Wp4, const float* __restrict__ bp,
    const float* __restrict__ h2, float* __restrict__ p_out,
    float* __restrict__ rd_out) {
  int tid = threadIdx.x;
  int lane = tid & 63;
  int ks = lane & 15;    // k-slice: floats 4*ks..4*ks+3 of the 64-wide row
  int osub = lane >> 4;  // which of 4 outputs this quarter-wave owns
  float4 h = ((const float4*)h2)[ks];
  int gwave = (blockIdx.x * 256 + tid) >> 6;  // 0..4095
  int obase0 = gwave * 64;
  for (int it = 0; it < 16; ++it) {
    int o = obase0 + it * 4 + osub;
    size_t idx = (size_t)o * 16 + ks;
    float4 a = Wro4[idx], b = Wri4[idx], c = Wp4[idx];
    float dro = a.x * h.x + a.y * h.y + a.z * h.z + a.w * h.w;
    float dri = b.x * h.x + b.y * h.y + b.z * h.z + b.w * h.w;
    float dp = c.x * h.x + c.y * h.y + c.z * h.z + c.w * h.w;
    for (int off = 8; off; off >>= 1) {
      dro += __shfl_xor(dro, off);
      dri += __shfl_xor(dri, off);
      dp += __shfl_xor(dp, off);
    }
    if (ks == 0) {
      float ro = 1.f / (1.f + __expf(-(dro + bro[o])));
      float ri = 1.f / (1.f + __expf(-(dri + bri[o])));
      float pv = 1.f / (1.f + __expf(-(dp + bp[o])));
      p_out[o] = pv;
      rd_out[o] = ri - ro;
    }
  }
}

// ---------------------------------------------------------------------------
// Value iteration, ONE launch. 32x32 output tile per block with halo=10:
// load 52x52 of p, rd into LDS, run 10 local iterations:
//   u = v*p + rd   (zero-padded; u ring stays 0)
//   v = max over 8 neighbors of u
// Core 32x32 remains exact because invalidity creeps 1 cell/iter from rim.
// ---------------------------------------------------------------------------
#define TILE 32
#define HALO 10
#define LR 52  // TILE + 2*HALO
__global__ __launch_bounds__(256) void valiter_kernel(
    const float* __restrict__ p, const float* __restrict__ rd,
    float* __restrict__ vout) {
  __shared__ float u[LR + 2][LR + 3];
  __shared__ float pp[LR][LR + 1];
  __shared__ float rr[LR][LR + 1];
  __shared__ float vv[LR][LR + 1];
  int tid = threadIdx.x;
  int ti = blockIdx.x >> 4, tj = blockIdx.x & 15;  // grid 256 = 16x16 tiles
  int gi0 = ti * TILE - HALO, gj0 = tj * TILE - HALO;
  for (int idx = tid; idx < (LR + 2) * (LR + 3); idx += 256)
    ((float*)u)[idx] = 0.f;
  for (int idx = tid; idx < LR * LR; idx += 256) {
    int i = idx / LR, j = idx % LR;
    int gi = gi0 + i, gj = gj0 + j;
    bool ok = (gi >= 0) & (gi < HW) & (gj >= 0) & (gj < HW);
    pp[i][j] = ok ? p[gi * HW + gj] : 0.f;
    rr[i][j] = ok ? rd[gi * HW + gj] : 0.f;
    vv[i][j] = 0.f;
  }
  __syncthreads();
  for (int k = 0; k < 10; ++k) {
    for (int idx = tid; idx < LR * LR; idx += 256) {
      int i = idx / LR, j = idx % LR;
      u[i + 1][j + 1] = vv[i][j] * pp[i][j] + rr[i][j];
    }
    __syncthreads();
    for (int idx = tid; idx < LR * LR; idx += 256) {
      int i = idx / LR, j = idx % LR;
      float m = u[i][j];
      m = fmaxf(m, u[i][j + 1]);
      m = fmaxf(m, u[i][j + 2]);
      m = fmaxf(m, u[i + 1][j]);
      m = fmaxf(m, u[i + 1][j + 2]);
      m = fmaxf(m, u[i + 2][j]);
      m = fmaxf(m, u[i + 2][j + 1]);
      m = fmaxf(m, u[i + 2][j + 2]);
      vv[i][j] = m;
    }
    __syncthreads();
  }
  for (int idx = tid; idx < TILE * TILE; idx += 256) {
    int a = idx >> 5, b = idx & 31;
    vout[(ti * TILE + a) * HW + tj * TILE + b] = vv[HALO + a][HALO + b];
  }
}

// ---------------------------------------------------------------------------
// Reduce pol partials -> hp = relu(+bpol); logits = Whead@hp + bhead;
// softmax -> out[0..7]; out[8] = v[pos]. One block.
// ---------------------------------------------------------------------------
__global__ __launch_bounds__(256) void finish_pol(
    const float* __restrict__ partials, const float* __restrict__ bpol,
    const float* __restrict__ Whead, const float* __restrict__ bhead,
    const float* __restrict__ v, const int* __restrict__ pos,
    float* __restrict__ out) {
  __shared__ float red[8][32];
  __shared__ float hp[32];
  __shared__ float logits[8];
  int tid = threadIdx.x;
  int row = tid & 31, grp = tid >> 5;
  float s = 0.f;
  for (int b = grp; b < GRID_MV; b += 8) s += partials[b * 32 + row];
  red[grp][row] = s;
  __syncthreads();
  if (tid < 32) {
    float t = bpol[tid];
    for (int g = 0; g < 8; ++g) t += red[g][tid];
    hp[tid] = fmaxf(t, 0.f);
  }
  __syncthreads();
  if (tid < 8) {
    float t = bhead[tid];
    for (int k = 0; k < 32; ++k) t += Whead[tid * 32 + k] * hp[k];
    logits[tid] = t;
  }
  __syncthreads();
  if (tid == 0) {
    float mx = logits[0];
    for (int j = 1; j < 8; ++j) mx = fmaxf(mx, logits[j]);
    float e[8], sum = 0.f;
    for (int j = 0; j < 8; ++j) {
      e[j] = __expf(logits[j] - mx);
      sum += e[j];
    }
    for (int j = 0; j < 8; ++j) out[j] = e[j] / sum;
    out[8] = v[pos[0] * HW + pos[1]];
  }
}

extern "C" void kernel_launch(void* const* d_in, const int* in_sizes, int n_in,
                              void* d_out, int out_size, void* d_ws,
                              size_t ws_size, hipStream_t stream) {
  const float* x = (const float*)d_in[0];
  const int* pos = (const int*)d_in[1];
  const float* W1 = (const float*)d_in[2];
  const float* b1 = (const float*)d_in[3];
  const float* W2 = (const float*)d_in[4];
  const float* b2 = (const float*)d_in[5];
  const float* Wro = (const float*)d_in[6];
  const float* bro = (const float*)d_in[7];
  const float* Wri = (const float*)d_in[8];
  const float* bri = (const float*)d_in[9];
  const float* Wp = (const float*)d_in[10];
  const float* bp = (const float*)d_in[11];
  const float* Wpol = (const float*)d_in[12];
  const float* bpol = (const float*)d_in[13];
  const float* Whead = (const float*)d_in[14];
  const float* bhead = (const float*)d_in[15];
  float* ws = (float*)d_ws;
  float* out = (float*)d_out;

  float* part1 = ws + WS_PART1;
  float* h2 = ws + WS_H2;
  float* pbuf = ws + WS_P;
  float* rdbuf = ws + WS_RD;
  float* vbuf = ws + WS_V;
  float* part2 = ws + WS_PART2;

  // h1 partials: W1 (32 x 786432) @ state
  matvec32_partials<<<GRID_MV, 256, 0, stream>>>(
      (const float4*)W1, (const float4*)x, NC4_1, (const float4*)x, NC4_1,
      CHUNK1, part1);
  // h1 -> h2
  finish_h<<<1, 256, 0, stream>>>(part1, b1, W2, b2, h2);
  // p, rd = sig(ri) - sig(ro)
  rop_kernel<<<1024, 256, 0, stream>>>((const float4*)Wro, bro,
                                       (const float4*)Wri, bri,
                                       (const float4*)Wp, bp, h2, pbuf, rdbuf);
  // 10 value-iteration steps in one launch
  valiter_kernel<<<256, 256, 0, stream>>>(pbuf, rdbuf, vbuf);
  // hp partials: Wpol (32 x 1048576) @ [v, state]
  matvec32_partials<<<GRID_MV, 256, 0, stream>>>(
      (const float4*)Wpol, (const float4*)vbuf, NSTATE / 4, (const float4*)x,
      NC4_P, CHUNKP, part2);
  // heads + softmax + state value
  finish_pol<<<1, 256, 0, stream>>>(part2, bpol, Whead, bhead, vbuf, pos, out);
}

// Round 2
// 188.994 us; speedup vs baseline: 1.0083x; 1.0083x over previous
//
#include <hip/hip_runtime.h>

#define HW 512
#define NSTATE (HW * HW)          // 262144
#define NC4_1 196608              // 786432/4  (3*H*W floats as float4)
#define NC4_P 262144              // 1048576/4 (4*H*W floats as float4)
#define GRID_MV 1024
#define CHUNK1 (NC4_1 / GRID_MV)  // 192
#define CHUNKP (NC4_P / GRID_MV)  // 256

// ws layout (float offsets)
#define WS_PART1 0
#define WS_H2 (32 * GRID_MV)          // 32768
#define WS_P (WS_H2 + 64)             // 32832
#define WS_RD (WS_P + NSTATE)         // 294976
#define WS_V (WS_RD + NSTATE)         // 557120
#define WS_PART2 (WS_V + NSTATE)      // 819264

// ---------------------------------------------------------------------------
// 32-row matvec partials. Loop order: column step outer, 8 rows inner ->
// 9 independent loads (1 x + 8 W) in flight per step, acc[8] in registers,
// single shuffle-reduce per row at the very end.
// ---------------------------------------------------------------------------
__global__ __launch_bounds__(256) void matvec32_partials(
    const float4* __restrict__ W4, const float4* __restrict__ A4, int lenA4,
    const float4* __restrict__ B4, int ncols4, int chunk4,
    float* __restrict__ partials) {
  int tid = threadIdx.x;
  int wave = tid >> 6, lane = tid & 63;
  int c0 = blockIdx.x * chunk4;
  const float4* Wbase = W4 + (size_t)(wave * 8) * ncols4;
  float acc[8] = {0.f, 0.f, 0.f, 0.f, 0.f, 0.f, 0.f, 0.f};
  for (int c = c0 + lane; c < c0 + chunk4; c += 64) {
    float4 x = (c < lenA4) ? A4[c] : B4[c - lenA4];
#pragma unroll
    for (int r = 0; r < 8; ++r) {
      float4 w = Wbase[(size_t)r * ncols4 + c];
      acc[r] += w.x * x.x + w.y * x.y + w.z * x.z + w.w * x.w;
    }
  }
#pragma unroll
  for (int r = 0; r < 8; ++r) {
    float a = acc[r];
    a += __shfl_xor(a, 32);
    a += __shfl_xor(a, 16);
    a += __shfl_xor(a, 8);
    a += __shfl_xor(a, 4);
    a += __shfl_xor(a, 2);
    a += __shfl_xor(a, 1);
    if (lane == 0) partials[blockIdx.x * 32 + wave * 8 + r] = a;
  }
}

// ---------------------------------------------------------------------------
// Reduce partials -> h1 = relu(W1@state+b1); h2 = relu(W2@h1+b2). One block.
// ---------------------------------------------------------------------------
__global__ __launch_bounds__(256) void finish_h(
    const float* __restrict__ partials, const float* __restrict__ b1,
    const float* __restrict__ W2, const float* __restrict__ b2,
    float* __restrict__ h2out) {
  __shared__ float red[8][32];
  __shared__ float h1[32];
  int tid = threadIdx.x;
  int row = tid & 31, grp = tid >> 5;
  float s = 0.f;
  for (int b = grp; b < GRID_MV; b += 8) s += partials[b * 32 + row];
  red[grp][row] = s;
  __syncthreads();
  if (tid < 32) {
    float t = b1[tid];
    for (int g = 0; g < 8; ++g) t += red[g][tid];
    h1[tid] = fmaxf(t, 0.f);
  }
  __syncthreads();
  if (tid < 64) {
    float t = b2[tid];
    for (int k = 0; k < 32; ++k) t += W2[tid * 32 + k] * h1[k];
    h2out[tid] = fmaxf(t, 0.f);
  }
}

// ---------------------------------------------------------------------------
// Fused r_out/r_in/p kernel, batched-load version. Each wave owns 64
// consecutive output rows (= 16 KB per matrix, fully contiguous). Per matrix:
// 16 independent 1KB wave-loads -> per-lane partial dots part[16] -> 16
// independent 4-step shfl_xor reduce chains -> LDS bounce of the 64 dots.
// Epilogue: all 64 lanes compute sigmoids, coalesced 4B stores.
// ---------------------------------------------------------------------------
__global__ __launch_bounds__(256) void rop_kernel(
    const float4* __restrict__ Wro4, const float* __restrict__ bro,
    const float4* __restrict__ Wri4, const float* __restrict__ bri,
    const float4* __restrict__ Wp4, const float* __restrict__ bp,
    const float* __restrict__ h2, float* __restrict__ p_out,
    float* __restrict__ rd_out) {
  __shared__ float dots[4][3][64];
  int tid = threadIdx.x;
  int wave = tid >> 6, lane = tid & 63;
  int ks = lane & 15, osub = lane >> 4;
  float4 h4 = ((const float4*)h2)[ks];
  int g = blockIdx.x * 4 + wave;   // wave group 0..4095
  size_t base = (size_t)g * 1024;  // first float4 of this wave's 64 rows
  const float4* mats[3] = {Wro4, Wri4, Wp4};
#pragma unroll
  for (int m = 0; m < 3; ++m) {
    const float4* __restrict__ W = mats[m];
    float part[16];
#pragma unroll
    for (int j = 0; j < 16; ++j) {
      float4 w = W[base + j * 64 + lane];
      part[j] = w.x * h4.x + w.y * h4.y + w.z * h4.z + w.w * h4.w;
    }
#pragma unroll
    for (int j = 0; j < 16; ++j) {
      part[j] += __shfl_xor(part[j], 8);
      part[j] += __shfl_xor(part[j], 4);
      part[j] += __shfl_xor(part[j], 2);
      part[j] += __shfl_xor(part[j], 1);
    }
    if (ks == 0) {
#pragma unroll
      for (int j = 0; j < 16; ++j) dots[wave][m][j * 4 + osub] = part[j];
    }
  }
  __syncthreads();
  int o = g * 64 + lane;
  float dro = dots[wave][0][lane] + bro[o];
  float dri = dots[wave][1][lane] + bri[o];
  float dp = dots[wave][2][lane] + bp[o];
  float sro = 1.f / (1.f + __expf(-dro));
  float sri = 1.f / (1.f + __expf(-dri));
  float pv = 1.f / (1.f + __expf(-dp));
  p_out[o] = pv;
  rd_out[o] = sri - sro;
}

// ---------------------------------------------------------------------------
// Value iteration, ONE launch. 32x32 output tile per block with halo=10:
// load 52x52 of p, rd into LDS, run 10 local iterations:
//   u = v*p + rd   (zero-padded; u ring stays 0)
//   v = max over 8 neighbors of u
// Core 32x32 remains exact because invalidity creeps 1 cell/iter from rim.
// ---------------------------------------------------------------------------
#define TILE 32
#define HALO 10
#define LR 52  // TILE + 2*HALO
__global__ __launch_bounds__(256) void valiter_kernel(
    const float* __restrict__ p, const float* __restrict__ rd,
    float* __restrict__ vout) {
  __shared__ float u[LR + 2][LR + 3];
  __shared__ float pp[LR][LR + 1];
  __shared__ float rr[LR][LR + 1];
  __shared__ float vv[LR][LR + 1];
  int tid = threadIdx.x;
  int ti = blockIdx.x >> 4, tj = blockIdx.x & 15;  // grid 256 = 16x16 tiles
  int gi0 = ti * TILE - HALO, gj0 = tj * TILE - HALO;
  for (int idx = tid; idx < (LR + 2) * (LR + 3); idx += 256)
    ((float*)u)[idx] = 0.f;
  for (int idx = tid; idx < LR * LR; idx += 256) {
    int i = idx / LR, j = idx % LR;
    int gi = gi0 + i, gj = gj0 + j;
    bool ok = (gi >= 0) & (gi < HW) & (gj >= 0) & (gj < HW);
    pp[i][j] = ok ? p[gi * HW + gj] : 0.f;
    rr[i][j] = ok ? rd[gi * HW + gj] : 0.f;
    vv[i][j] = 0.f;
  }
  __syncthreads();
  for (int k = 0; k < 10; ++k) {
    for (int idx = tid; idx < LR * LR; idx += 256) {
      int i = idx / LR, j = idx % LR;
      u[i + 1][j + 1] = vv[i][j] * pp[i][j] + rr[i][j];
    }
    __syncthreads();
    for (int idx = tid; idx < LR * LR; idx += 256) {
      int i = idx / LR, j = idx % LR;
      float m = u[i][j];
      m = fmaxf(m, u[i][j + 1]);
      m = fmaxf(m, u[i][j + 2]);
      m = fmaxf(m, u[i + 1][j]);
      m = fmaxf(m, u[i + 1][j + 2]);
      m = fmaxf(m, u[i + 2][j]);
      m = fmaxf(m, u[i + 2][j + 1]);
      m = fmaxf(m, u[i + 2][j + 2]);
      vv[i][j] = m;
    }
    __syncthreads();
  }
  for (int idx = tid; idx < TILE * TILE; idx += 256) {
    int a = idx >> 5, b = idx & 31;
    vout[(ti * TILE + a) * HW + tj * TILE + b] = vv[HALO + a][HALO + b];
  }
}

// ---------------------------------------------------------------------------
// Reduce pol partials -> hp = relu(+bpol); logits = Whead@hp + bhead;
// softmax -> out[0..7]; out[8] = v[pos]. One block.
// ---------------------------------------------------------------------------
__global__ __launch_bounds__(256) void finish_pol(
    const float* __restrict__ partials, const float* __restrict__ bpol,
    const float* __restrict__ Whead, const float* __restrict__ bhead,
    const float* __restrict__ v, const int* __restrict__ pos,
    float* __restrict__ out) {
  __shared__ float red[8][32];
  __shared__ float hp[32];
  __shared__ float logits[8];
  int tid = threadIdx.x;
  int row = tid & 31, grp = tid >> 5;
  float s = 0.f;
  for (int b = grp; b < GRID_MV; b += 8) s += partials[b * 32 + row];
  red[grp][row] = s;
  __syncthreads();
  if (tid < 32) {
    float t = bpol[tid];
    for (int g = 0; g < 8; ++g) t += red[g][tid];
    hp[tid] = fmaxf(t, 0.f);
  }
  __syncthreads();
  if (tid < 8) {
    float t = bhead[tid];
    for (int k = 0; k < 32; ++k) t += Whead[tid * 32 + k] * hp[k];
    logits[tid] = t;
  }
  __syncthreads();
  if (tid == 0) {
    float mx = logits[0];
    for (int j = 1; j < 8; ++j) mx = fmaxf(mx, logits[j]);
    float e[8], sum = 0.f;
    for (int j = 0; j < 8; ++j) {
      e[j] = __expf(logits[j] - mx);
      sum += e[j];
    }
    for (int j = 0; j < 8; ++j) out[j] = e[j] / sum;
    out[8] = v[pos[0] * HW + pos[1]];
  }
}

extern "C" void kernel_launch(void* const* d_in, const int* in_sizes, int n_in,
                              void* d_out, int out_size, void* d_ws,
                              size_t ws_size, hipStream_t stream) {
  const float* x = (const float*)d_in[0];
  const int* pos = (const int*)d_in[1];
  const float* W1 = (const float*)d_in[2];
  const float* b1 = (const float*)d_in[3];
  const float* W2 = (const float*)d_in[4];
  const float* b2 = (const float*)d_in[5];
  const float* Wro = (const float*)d_in[6];
  const float* bro = (const float*)d_in[7];
  const float* Wri = (const float*)d_in[8];
  const float* bri = (const float*)d_in[9];
  const float* Wp = (const float*)d_in[10];
  const float* bp = (const float*)d_in[11];
  const float* Wpol = (const float*)d_in[12];
  const float* bpol = (const float*)d_in[13];
  const float* Whead = (const float*)d_in[14];
  const float* bhead = (const float*)d_in[15];
  float* ws = (float*)d_ws;
  float* out = (float*)d_out;

  float* part1 = ws + WS_PART1;
  float* h2 = ws + WS_H2;
  float* pbuf = ws + WS_P;
  float* rdbuf = ws + WS_RD;
  float* vbuf = ws + WS_V;
  float* part2 = ws + WS_PART2;

  // h1 partials: W1 (32 x 786432) @ state
  matvec32_partials<<<GRID_MV, 256, 0, stream>>>(
      (const float4*)W1, (const float4*)x, NC4_1, (const float4*)x, NC4_1,
      CHUNK1, part1);
  // h1 -> h2
  finish_h<<<1, 256, 0, stream>>>(part1, b1, W2, b2, h2);
  // p, rd = sig(ri) - sig(ro)
  rop_kernel<<<1024, 256, 0, stream>>>((const float4*)Wro, bro,
                                       (const float4*)Wri, bri,
                                       (const float4*)Wp, bp, h2, pbuf, rdbuf);
  // 10 value-iteration steps in one launch
  valiter_kernel<<<256, 256, 0, stream>>>(pbuf, rdbuf, vbuf);
  // hp partials: Wpol (32 x 1048576) @ [v, state]
  matvec32_partials<<<GRID_MV, 256, 0, stream>>>(
      (const float4*)Wpol, (const float4*)vbuf, NSTATE / 4, (const float4*)x,
      NC4_P, CHUNKP, part2);
  // heads + softmax + state value
  finish_pol<<<1, 256, 0, stream>>>(part2, bpol, Whead, bhead, vbuf, pos, out);
}

// Round 3
// 187.756 us; speedup vs baseline: 1.0149x; 1.0066x over previous
//
#include <hip/hip_runtime.h>

#define HW 512
#define NSTATE (HW * HW)   // 262144
#define NC4_X 196608       // 786432/4: x as float4
#define NC4_POLROW 262144  // Wpol row stride in float4 (1048576/4)
#define NC4_V 65536        // v as float4
#define GRID_MV 1024
#define CHUNK_K1 192  // 196608/1024 float4 per block
#define CHUNK_PV 256  // 65536/256 float4 per block
#define GRID_PV 256

// ws layout (float offsets); all float4-aligned
#define WS_PART1 0                    // 1024*32
#define WS_PARTPX 32768               // 1024*32
#define WS_PARTPV 65536               // 256*32
#define WS_H2 73728                   // 64
#define WS_P 73792                    // 262144
#define WS_RD (WS_P + NSTATE)         // 262144
#define WS_V (WS_RD + NSTATE)         // 262144

// ---------------------------------------------------------------------------
// K1: fused partials for W1@x (blocks 0..1023) and Wpol[:, v-cols skipped]@x
// (blocks 1024..2047). 4 waves x 8 rows; 9 independent loads in flight per
// column step; acc[8] in registers; one shuffle-reduce at the end.
// ---------------------------------------------------------------------------
__global__ __launch_bounds__(256) void mv_dual(
    const float4* __restrict__ W1, const float4* __restrict__ Wpol,
    const float4* __restrict__ x, float* __restrict__ part1,
    float* __restrict__ partPx) {
  int b = blockIdx.x;
  const float4* __restrict__ W;
  float* __restrict__ outp;
  int ncols4, bb;
  if (b < GRID_MV) {
    W = W1; outp = part1; ncols4 = NC4_X; bb = b;
  } else {
    W = Wpol + NC4_V;  // skip v columns (v is FIRST in concat([v, state]))
    outp = partPx; ncols4 = NC4_POLROW; bb = b - GRID_MV;
  }
  int tid = threadIdx.x;
  int wave = tid >> 6, lane = tid & 63;
  int c0 = bb * CHUNK_K1;
  const float4* Wbase = W + (size_t)(wave * 8) * ncols4;
  float acc[8] = {0.f, 0.f, 0.f, 0.f, 0.f, 0.f, 0.f, 0.f};
  for (int c = c0 + lane; c < c0 + CHUNK_K1; c += 64) {
    float4 xv = x[c];
#pragma unroll
    for (int r = 0; r < 8; ++r) {
      float4 w = Wbase[(size_t)r * ncols4 + c];
      acc[r] += w.x * xv.x + w.y * xv.y + w.z * xv.z + w.w * xv.w;
    }
  }
#pragma unroll
  for (int r = 0; r < 8; ++r) {
    float a = acc[r];
    a += __shfl_xor(a, 32);
    a += __shfl_xor(a, 16);
    a += __shfl_xor(a, 8);
    a += __shfl_xor(a, 4);
    a += __shfl_xor(a, 2);
    a += __shfl_xor(a, 1);
    if (lane == 0) outp[bb * 32 + wave * 8 + r] = a;
  }
}

// ---------------------------------------------------------------------------
// K5: partials for Wpol[:, 0:262144] @ v. 256 blocks, chunk 256 float4.
// ---------------------------------------------------------------------------
__global__ __launch_bounds__(256) void mv_polv(
    const float4* __restrict__ Wpol, const float4* __restrict__ v,
    float* __restrict__ partPv) {
  int tid = threadIdx.x;
  int wave = tid >> 6, lane = tid & 63;
  int c0 = blockIdx.x * CHUNK_PV;
  const float4* Wbase = Wpol + (size_t)(wave * 8) * NC4_POLROW;
  float acc[8] = {0.f, 0.f, 0.f, 0.f, 0.f, 0.f, 0.f, 0.f};
  for (int c = c0 + lane; c < c0 + CHUNK_PV; c += 64) {
    float4 xv = v[c];
#pragma unroll
    for (int r = 0; r < 8; ++r) {
      float4 w = Wbase[(size_t)r * NC4_POLROW + c];
      acc[r] += w.x * xv.x + w.y * xv.y + w.z * xv.z + w.w * xv.w;
    }
  }
#pragma unroll
  for (int r = 0; r < 8; ++r) {
    float a = acc[r];
    a += __shfl_xor(a, 32);
    a += __shfl_xor(a, 16);
    a += __shfl_xor(a, 8);
    a += __shfl_xor(a, 4);
    a += __shfl_xor(a, 2);
    a += __shfl_xor(a, 1);
    if (lane == 0) partPv[blockIdx.x * 32 + wave * 8 + r] = a;
  }
}

// ---------------------------------------------------------------------------
// finish_h: reduce part1 -> h1 = relu(W1@x+b1); h2 = relu(W2@h1+b2).
// ---------------------------------------------------------------------------
__global__ __launch_bounds__(256) void finish_h(
    const float* __restrict__ partials, const float* __restrict__ b1,
    const float* __restrict__ W2, const float* __restrict__ b2,
    float* __restrict__ h2out) {
  __shared__ float red[8][32];
  __shared__ float h1[32];
  int tid = threadIdx.x;
  int row = tid & 31, grp = tid >> 5;
  float s = 0.f;
  for (int b = grp; b < GRID_MV; b += 8) s += partials[b * 32 + row];
  red[grp][row] = s;
  __syncthreads();
  if (tid < 32) {
    float t = b1[tid];
    for (int g = 0; g < 8; ++g) t += red[g][tid];
    h1[tid] = fmaxf(t, 0.f);
  }
  __syncthreads();
  if (tid < 64) {
    float t = b2[tid];
    for (int k = 0; k < 32; ++k) t += W2[tid * 32 + k] * h1[k];
    h2out[tid] = fmaxf(t, 0.f);
  }
}

// ---------------------------------------------------------------------------
// rop: p = sig(Wp@h2+bp), rd = sig(Wri@h2+bri) - sig(Wro@h2+bro).
// Per wave: 64 consecutive rows per matrix = 16KB contiguous, 16 independent
// 1KB wave-loads -> part[16] -> 16 independent 4-step reduces -> LDS bounce.
// ---------------------------------------------------------------------------
__global__ __launch_bounds__(256) void rop_kernel(
    const float4* __restrict__ Wro4, const float* __restrict__ bro,
    const float4* __restrict__ Wri4, const float* __restrict__ bri,
    const float4* __restrict__ Wp4, const float* __restrict__ bp,
    const float* __restrict__ h2, float* __restrict__ p_out,
    float* __restrict__ rd_out) {
  __shared__ float dots[4][3][64];
  int tid = threadIdx.x;
  int wave = tid >> 6, lane = tid & 63;
  int ks = lane & 15, osub = lane >> 4;
  float4 h4 = ((const float4*)h2)[ks];
  int g = blockIdx.x * 4 + wave;   // 0..4095
  size_t base = (size_t)g * 1024;  // first float4 of this wave's 64 rows
  const float4* mats[3] = {Wro4, Wri4, Wp4};
#pragma unroll
  for (int m = 0; m < 3; ++m) {
    const float4* __restrict__ W = mats[m];
    float part[16];
#pragma unroll
    for (int j = 0; j < 16; ++j) {
      float4 w = W[base + j * 64 + lane];
      part[j] = w.x * h4.x + w.y * h4.y + w.z * h4.z + w.w * h4.w;
    }
#pragma unroll
    for (int j = 0; j < 16; ++j) {
      part[j] += __shfl_xor(part[j], 8);
      part[j] += __shfl_xor(part[j], 4);
      part[j] += __shfl_xor(part[j], 2);
      part[j] += __shfl_xor(part[j], 1);
    }
    if (ks == 0) {
#pragma unroll
      for (int j = 0; j < 16; ++j) dots[wave][m][j * 4 + osub] = part[j];
    }
  }
  __syncthreads();
  int o = g * 64 + lane;
  float dro = dots[wave][0][lane] + bro[o];
  float dri = dots[wave][1][lane] + bri[o];
  float dp = dots[wave][2][lane] + bp[o];
  float sro = 1.f / (1.f + __expf(-dro));
  float sri = 1.f / (1.f + __expf(-dri));
  float pv = 1.f / (1.f + __expf(-dp));
  p_out[o] = pv;
  rd_out[o] = sri - sro;
}

// ---------------------------------------------------------------------------
// Value iteration, ONE launch, 1024 blocks (4/CU). 16x16 output tile with
// halo=10 -> 36x36 region in LDS, 10 local iterations:
//   u = v*p + rd (zero ring), v = 8-neighbor max of u.
// Invalidity creeps 1 cell/iter from region rim; 36-2*10=16 core stays exact.
// ---------------------------------------------------------------------------
#define TILE 16
#define HALO 10
#define LR 36  // TILE + 2*HALO
__global__ __launch_bounds__(256) void valiter_kernel(
    const float* __restrict__ p, const float* __restrict__ rd,
    float* __restrict__ vout) {
  __shared__ float u[LR + 2][LR + 3];
  __shared__ float pp[LR][LR + 1];
  __shared__ float rr[LR][LR + 1];
  __shared__ float vv[LR][LR + 1];
  int tid = threadIdx.x;
  int ti = blockIdx.x >> 5, tj = blockIdx.x & 31;  // 32x32 tiles
  int gi0 = ti * TILE - HALO, gj0 = tj * TILE - HALO;
  for (int idx = tid; idx < (LR + 2) * (LR + 3); idx += 256)
    ((float*)u)[idx] = 0.f;
  for (int idx = tid; idx < LR * LR; idx += 256) {
    int i = idx / LR, j = idx % LR;
    int gi = gi0 + i, gj = gj0 + j;
    bool ok = (gi >= 0) & (gi < HW) & (gj >= 0) & (gj < HW);
    pp[i][j] = ok ? p[gi * HW + gj] : 0.f;
    rr[i][j] = ok ? rd[gi * HW + gj] : 0.f;
    vv[i][j] = 0.f;
  }
  __syncthreads();
  for (int k = 0; k < 10; ++k) {
#pragma unroll
    for (int idx = tid; idx < LR * LR; idx += 256) {
      int i = idx / LR, j = idx % LR;
      u[i + 1][j + 1] = vv[i][j] * pp[i][j] + rr[i][j];
    }
    __syncthreads();
#pragma unroll
    for (int idx = tid; idx < LR * LR; idx += 256) {
      int i = idx / LR, j = idx % LR;
      float m = u[i][j];
      m = fmaxf(m, u[i][j + 1]);
      m = fmaxf(m, u[i][j + 2]);
      m = fmaxf(m, u[i + 1][j]);
      m = fmaxf(m, u[i + 1][j + 2]);
      m = fmaxf(m, u[i + 2][j]);
      m = fmaxf(m, u[i + 2][j + 1]);
      m = fmaxf(m, u[i + 2][j + 2]);
      vv[i][j] = m;
    }
    __syncthreads();
  }
  // core 16x16 writeout: one output per thread
  if (tid < TILE * TILE) {
    int a = tid >> 4, b = tid & 15;
    vout[(ti * TILE + a) * HW + tj * TILE + b] = vv[HALO + a][HALO + b];
  }
}

// ---------------------------------------------------------------------------
// finish_pol: hp = relu(bpol + sum partPx + sum partPv); logits = Whead@hp +
// bhead; softmax -> out[0..7]; out[8] = v[pos].
// ---------------------------------------------------------------------------
__global__ __launch_bounds__(256) void finish_pol(
    const float* __restrict__ partPx, const float* __restrict__ partPv,
    const float* __restrict__ bpol, const float* __restrict__ Whead,
    const float* __restrict__ bhead, const float* __restrict__ v,
    const int* __restrict__ pos, float* __restrict__ out) {
  __shared__ float red[8][32];
  __shared__ float hp[32];
  __shared__ float logits[8];
  int tid = threadIdx.x;
  int row = tid & 31, grp = tid >> 5;
  float s = 0.f;
  for (int b = grp; b < GRID_MV; b += 8) s += partPx[b * 32 + row];
  for (int b = grp; b < GRID_PV; b += 8) s += partPv[b * 32 + row];
  red[grp][row] = s;
  __syncthreads();
  if (tid < 32) {
    float t = bpol[tid];
    for (int g = 0; g < 8; ++g) t += red[g][tid];
    hp[tid] = fmaxf(t, 0.f);
  }
  __syncthreads();
  if (tid < 8) {
    float t = bhead[tid];
    for (int k = 0; k < 32; ++k) t += Whead[tid * 32 + k] * hp[k];
    logits[tid] = t;
  }
  __syncthreads();
  if (tid == 0) {
    float mx = logits[0];
    for (int j = 1; j < 8; ++j) mx = fmaxf(mx, logits[j]);
    float e[8], sum = 0.f;
    for (int j = 0; j < 8; ++j) {
      e[j] = __expf(logits[j] - mx);
      sum += e[j];
    }
    for (int j = 0; j < 8; ++j) out[j] = e[j] / sum;
    out[8] = v[pos[0] * HW + pos[1]];
  }
}

extern "C" void kernel_launch(void* const* d_in, const int* in_sizes, int n_in,
                              void* d_out, int out_size, void* d_ws,
                              size_t ws_size, hipStream_t stream) {
  const float* x = (const float*)d_in[0];
  const int* pos = (const int*)d_in[1];
  const float* W1 = (const float*)d_in[2];
  const float* b1 = (const float*)d_in[3];
  const float* W2 = (const float*)d_in[4];
  const float* b2 = (const float*)d_in[5];
  const float* Wro = (const float*)d_in[6];
  const float* bro = (const float*)d_in[7];
  const float* Wri = (const float*)d_in[8];
  const float* bri = (const float*)d_in[9];
  const float* Wp = (const float*)d_in[10];
  const float* bp = (const float*)d_in[11];
  const float* Wpol = (const float*)d_in[12];
  const float* bpol = (const float*)d_in[13];
  const float* Whead = (const float*)d_in[14];
  const float* bhead = (const float*)d_in[15];
  float* ws = (float*)d_ws;
  float* out = (float*)d_out;

  float* part1 = ws + WS_PART1;
  float* partPx = ws + WS_PARTPX;
  float* partPv = ws + WS_PARTPV;
  float* h2 = ws + WS_H2;
  float* pbuf = ws + WS_P;
  float* rdbuf = ws + WS_RD;
  float* vbuf = ws + WS_V;

  // K1: W1@x partials AND Wpol x-column partials (independent of v)
  mv_dual<<<2 * GRID_MV, 256, 0, stream>>>(
      (const float4*)W1, (const float4*)Wpol, (const float4*)x, part1, partPx);
  // K2: h1 -> h2
  finish_h<<<1, 256, 0, stream>>>(part1, b1, W2, b2, h2);
  // K3: p, rd
  rop_kernel<<<1024, 256, 0, stream>>>((const float4*)Wro, bro,
                                       (const float4*)Wri, bri,
                                       (const float4*)Wp, bp, h2, pbuf, rdbuf);
  // K4: 10 value-iteration steps, one launch
  valiter_kernel<<<1024, 256, 0, stream>>>(pbuf, rdbuf, vbuf);
  // K5: Wpol v-column partials
  mv_polv<<<GRID_PV, 256, 0, stream>>>((const float4*)Wpol, (const float4*)vbuf,
                                       partPv);
  // K6: heads + softmax + state value
  finish_pol<<<1, 256, 0, stream>>>(partPx, partPv, bpol, Whead, bhead, vbuf,
                                    pos, out);
}

// Round 4
// 187.506 us; speedup vs baseline: 1.0163x; 1.0013x over previous
//
#include <hip/hip_runtime.h>

#define HW 512
#define NSTATE (HW * HW)   // 262144
#define NC4_X 196608       // 786432/4: x as float4
#define NC4_POLROW 262144  // Wpol row stride in float4 (1048576/4)
#define NC4_V 65536        // v as float4
#define GRID_MV 1024
#define CHUNK_K1 192  // 196608/1024 float4 per block
#define CHUNK_PV 256  // 65536/256 float4 per block
#define GRID_PV 256

// ws layout (float offsets); all float4-aligned
#define WS_PART1 0                    // 1024*32
#define WS_PARTPX 32768               // 1024*32
#define WS_PARTPV 65536               // 256*32
#define WS_H2 73728                   // 64
#define WS_P 73792                    // 262144
#define WS_RD (WS_P + NSTATE)
#define WS_V (WS_RD + NSTATE)

// ---------------------------------------------------------------------------
// K1: fused partials for W1@x (blocks 0..1023) and Wpol[:, x-cols]@x
// (blocks 1024..2047). 4 waves x 8 rows. __launch_bounds__(256,4) gives the
// compiler ~128 VGPRs so the 9 independent float4 loads per column step are
// actually issued together (R3: VGPR=32 serialized them -> 16% BW).
// ---------------------------------------------------------------------------
__global__ __launch_bounds__(256, 4) void mv_dual(
    const float4* __restrict__ W1, const float4* __restrict__ Wpol,
    const float4* __restrict__ x, float* __restrict__ part1,
    float* __restrict__ partPx) {
  int b = blockIdx.x;
  const float4* __restrict__ W;
  float* __restrict__ outp;
  int ncols4, bb;
  if (b < GRID_MV) {
    W = W1; outp = part1; ncols4 = NC4_X; bb = b;
  } else {
    W = Wpol + NC4_V;  // skip v columns (v is FIRST in concat([v, state]))
    outp = partPx; ncols4 = NC4_POLROW; bb = b - GRID_MV;
  }
  int tid = threadIdx.x;
  int wave = tid >> 6, lane = tid & 63;
  int c0 = bb * CHUNK_K1;
  const float4* Wbase = W + (size_t)(wave * 8) * ncols4;
  float acc[8] = {0.f, 0.f, 0.f, 0.f, 0.f, 0.f, 0.f, 0.f};
  for (int c = c0 + lane; c < c0 + CHUNK_K1; c += 64) {
    float4 xv = x[c];
    float4 w[8];
#pragma unroll
    for (int r = 0; r < 8; ++r) w[r] = Wbase[(size_t)r * ncols4 + c];
#pragma unroll
    for (int r = 0; r < 8; ++r)
      acc[r] += w[r].x * xv.x + w[r].y * xv.y + w[r].z * xv.z + w[r].w * xv.w;
  }
#pragma unroll
  for (int r = 0; r < 8; ++r) {
    float a = acc[r];
    a += __shfl_xor(a, 32);
    a += __shfl_xor(a, 16);
    a += __shfl_xor(a, 8);
    a += __shfl_xor(a, 4);
    a += __shfl_xor(a, 2);
    a += __shfl_xor(a, 1);
    if (lane == 0) outp[bb * 32 + wave * 8 + r] = a;
  }
}

// ---------------------------------------------------------------------------
// K5: partials for Wpol[:, 0:262144] @ v. 256 blocks, chunk 256 float4.
// ---------------------------------------------------------------------------
__global__ __launch_bounds__(256, 4) void mv_polv(
    const float4* __restrict__ Wpol, const float4* __restrict__ v,
    float* __restrict__ partPv) {
  int tid = threadIdx.x;
  int wave = tid >> 6, lane = tid & 63;
  int c0 = blockIdx.x * CHUNK_PV;
  const float4* Wbase = Wpol + (size_t)(wave * 8) * NC4_POLROW;
  float acc[8] = {0.f, 0.f, 0.f, 0.f, 0.f, 0.f, 0.f, 0.f};
  for (int c = c0 + lane; c < c0 + CHUNK_PV; c += 64) {
    float4 xv = v[c];
    float4 w[8];
#pragma unroll
    for (int r = 0; r < 8; ++r) w[r] = Wbase[(size_t)r * NC4_POLROW + c];
#pragma unroll
    for (int r = 0; r < 8; ++r)
      acc[r] += w[r].x * xv.x + w[r].y * xv.y + w[r].z * xv.z + w[r].w * xv.w;
  }
#pragma unroll
  for (int r = 0; r < 8; ++r) {
    float a = acc[r];
    a += __shfl_xor(a, 32);
    a += __shfl_xor(a, 16);
    a += __shfl_xor(a, 8);
    a += __shfl_xor(a, 4);
    a += __shfl_xor(a, 2);
    a += __shfl_xor(a, 1);
    if (lane == 0) partPv[blockIdx.x * 32 + wave * 8 + r] = a;
  }
}

// ---------------------------------------------------------------------------
// finish_h: reduce part1 -> h1 = relu(W1@x+b1); h2 = relu(W2@h1+b2).
// ---------------------------------------------------------------------------
__global__ __launch_bounds__(256) void finish_h(
    const float* __restrict__ partials, const float* __restrict__ b1,
    const float* __restrict__ W2, const float* __restrict__ b2,
    float* __restrict__ h2out) {
  __shared__ float red[8][32];
  __shared__ float h1[32];
  int tid = threadIdx.x;
  int row = tid & 31, grp = tid >> 5;
  float s = 0.f;
  for (int b = grp; b < GRID_MV; b += 8) s += partials[b * 32 + row];
  red[grp][row] = s;
  __syncthreads();
  if (tid < 32) {
    float t = b1[tid];
    for (int g = 0; g < 8; ++g) t += red[g][tid];
    h1[tid] = fmaxf(t, 0.f);
  }
  __syncthreads();
  if (tid < 64) {
    float t = b2[tid];
    for (int k = 0; k < 32; ++k) t += W2[tid * 32 + k] * h1[k];
    h2out[tid] = fmaxf(t, 0.f);
  }
}

// ---------------------------------------------------------------------------
// rop: p = sig(Wp@h2+bp), rd = sig(Wri@h2+bri) - sig(Wro@h2+bro).
// Per wave: 64 consecutive rows per matrix = 16KB contiguous, 16 independent
// 1KB wave-loads -> part[16] -> 16 independent 4-step reduces -> LDS bounce.
// ---------------------------------------------------------------------------
__global__ __launch_bounds__(256, 4) void rop_kernel(
    const float4* __restrict__ Wro4, const float* __restrict__ bro,
    const float4* __restrict__ Wri4, const float* __restrict__ bri,
    const float4* __restrict__ Wp4, const float* __restrict__ bp,
    const float* __restrict__ h2, float* __restrict__ p_out,
    float* __restrict__ rd_out) {
  __shared__ float dots[4][3][64];
  int tid = threadIdx.x;
  int wave = tid >> 6, lane = tid & 63;
  int ks = lane & 15, osub = lane >> 4;
  float4 h4 = ((const float4*)h2)[ks];
  int g = blockIdx.x * 4 + wave;   // 0..4095
  size_t base = (size_t)g * 1024;  // first float4 of this wave's 64 rows
  const float4* mats[3] = {Wro4, Wri4, Wp4};
#pragma unroll
  for (int m = 0; m < 3; ++m) {
    const float4* __restrict__ W = mats[m];
    float4 w[16];
#pragma unroll
    for (int j = 0; j < 16; ++j) w[j] = W[base + j * 64 + lane];
    float part[16];
#pragma unroll
    for (int j = 0; j < 16; ++j)
      part[j] = w[j].x * h4.x + w[j].y * h4.y + w[j].z * h4.z + w[j].w * h4.w;
#pragma unroll
    for (int j = 0; j < 16; ++j) {
      part[j] += __shfl_xor(part[j], 8);
      part[j] += __shfl_xor(part[j], 4);
      part[j] += __shfl_xor(part[j], 2);
      part[j] += __shfl_xor(part[j], 1);
    }
    if (ks == 0) {
#pragma unroll
      for (int j = 0; j < 16; ++j) dots[wave][m][j * 4 + osub] = part[j];
    }
  }
  __syncthreads();
  int o = g * 64 + lane;
  float dro = dots[wave][0][lane] + bro[o];
  float dri = dots[wave][1][lane] + bri[o];
  float dp = dots[wave][2][lane] + bp[o];
  float sro = 1.f / (1.f + __expf(-dro));
  float sri = 1.f / (1.f + __expf(-dri));
  float pv = 1.f / (1.f + __expf(-dp));
  p_out[o] = pv;
  rd_out[o] = sri - sro;
}

// ---------------------------------------------------------------------------
// Value iteration, ONE launch, 1024 blocks (4/CU). 16x16 output tile with
// halo=10 -> 36x36 region in LDS, 10 local iterations:
//   u = v*p + rd (zero ring), v = 8-neighbor max of u.
// Invalidity creeps 1 cell/iter from region rim; 36-2*10=16 core stays exact.
// ---------------------------------------------------------------------------
#define TILE 16
#define HALO 10
#define LR 36  // TILE + 2*HALO
__global__ __launch_bounds__(256) void valiter_kernel(
    const float* __restrict__ p, const float* __restrict__ rd,
    float* __restrict__ vout) {
  __shared__ float u[LR + 2][LR + 3];
  __shared__ float pp[LR][LR + 1];
  __shared__ float rr[LR][LR + 1];
  __shared__ float vv[LR][LR + 1];
  int tid = threadIdx.x;
  int ti = blockIdx.x >> 5, tj = blockIdx.x & 31;  // 32x32 tiles
  int gi0 = ti * TILE - HALO, gj0 = tj * TILE - HALO;
  for (int idx = tid; idx < (LR + 2) * (LR + 3); idx += 256)
    ((float*)u)[idx] = 0.f;
  for (int idx = tid; idx < LR * LR; idx += 256) {
    int i = idx / LR, j = idx % LR;
    int gi = gi0 + i, gj = gj0 + j;
    bool ok = (gi >= 0) & (gi < HW) & (gj >= 0) & (gj < HW);
    pp[i][j] = ok ? p[gi * HW + gj] : 0.f;
    rr[i][j] = ok ? rd[gi * HW + gj] : 0.f;
    vv[i][j] = 0.f;
  }
  __syncthreads();
  for (int k = 0; k < 10; ++k) {
#pragma unroll
    for (int idx = tid; idx < LR * LR; idx += 256) {
      int i = idx / LR, j = idx % LR;
      u[i + 1][j + 1] = vv[i][j] * pp[i][j] + rr[i][j];
    }
    __syncthreads();
#pragma unroll
    for (int idx = tid; idx < LR * LR; idx += 256) {
      int i = idx / LR, j = idx % LR;
      float m = u[i][j];
      m = fmaxf(m, u[i][j + 1]);
      m = fmaxf(m, u[i][j + 2]);
      m = fmaxf(m, u[i + 1][j]);
      m = fmaxf(m, u[i + 1][j + 2]);
      m = fmaxf(m, u[i + 2][j]);
      m = fmaxf(m, u[i + 2][j + 1]);
      m = fmaxf(m, u[i + 2][j + 2]);
      vv[i][j] = m;
    }
    __syncthreads();
  }
  if (tid < TILE * TILE) {
    int a = tid >> 4, b = tid & 15;
    vout[(ti * TILE + a) * HW + tj * TILE + b] = vv[HALO + a][HALO + b];
  }
}

// ---------------------------------------------------------------------------
// finish_pol: hp = relu(bpol + sum partPx + sum partPv); logits = Whead@hp +
// bhead; softmax -> out[0..7]; out[8] = v[pos].
// ---------------------------------------------------------------------------
__global__ __launch_bounds__(256) void finish_pol(
    const float* __restrict__ partPx, const float* __restrict__ partPv,
    const float* __restrict__ bpol, const float* __restrict__ Whead,
    const float* __restrict__ bhead, const float* __restrict__ v,
    const int* __restrict__ pos, float* __restrict__ out) {
  __shared__ float red[8][32];
  __shared__ float hp[32];
  __shared__ float logits[8];
  int tid = threadIdx.x;
  int row = tid & 31, grp = tid >> 5;
  float s = 0.f;
  for (int b = grp; b < GRID_MV; b += 8) s += partPx[b * 32 + row];
  for (int b = grp; b < GRID_PV; b += 8) s += partPv[b * 32 + row];
  red[grp][row] = s;
  __syncthreads();
  if (tid < 32) {
    float t = bpol[tid];
    for (int g = 0; g < 8; ++g) t += red[g][tid];
    hp[tid] = fmaxf(t, 0.f);
  }
  __syncthreads();
  if (tid < 8) {
    float t = bhead[tid];
    for (int k = 0; k < 32; ++k) t += Whead[tid * 32 + k] * hp[k];
    logits[tid] = t;
  }
  __syncthreads();
  if (tid == 0) {
    float mx = logits[0];
    for (int j = 1; j < 8; ++j) mx = fmaxf(mx, logits[j]);
    float e[8], sum = 0.f;
    for (int j = 0; j < 8; ++j) {
      e[j] = __expf(logits[j] - mx);
      sum += e[j];
    }
    for (int j = 0; j < 8; ++j) out[j] = e[j] / sum;
    out[8] = v[pos[0] * HW + pos[1]];
  }
}

extern "C" void kernel_launch(void* const* d_in, const int* in_sizes, int n_in,
                              void* d_out, int out_size, void* d_ws,
                              size_t ws_size, hipStream_t stream) {
  const float* x = (const float*)d_in[0];
  const int* pos = (const int*)d_in[1];
  const float* W1 = (const float*)d_in[2];
  const float* b1 = (const float*)d_in[3];
  const float* W2 = (const float*)d_in[4];
  const float* b2 = (const float*)d_in[5];
  const float* Wro = (const float*)d_in[6];
  const float* bro = (const float*)d_in[7];
  const float* Wri = (const float*)d_in[8];
  const float* bri = (const float*)d_in[9];
  const float* Wp = (const float*)d_in[10];
  const float* bp = (const float*)d_in[11];
  const float* Wpol = (const float*)d_in[12];
  const float* bpol = (const float*)d_in[13];
  const float* Whead = (const float*)d_in[14];
  const float* bhead = (const float*)d_in[15];
  float* ws = (float*)d_ws;
  float* out = (float*)d_out;

  float* part1 = ws + WS_PART1;
  float* partPx = ws + WS_PARTPX;
  float* partPv = ws + WS_PARTPV;
  float* h2 = ws + WS_H2;
  float* pbuf = ws + WS_P;
  float* rdbuf = ws + WS_RD;
  float* vbuf = ws + WS_V;

  // K1: W1@x partials AND Wpol x-column partials (independent of v)
  mv_dual<<<2 * GRID_MV, 256, 0, stream>>>(
      (const float4*)W1, (const float4*)Wpol, (const float4*)x, part1, partPx);
  // K2: h1 -> h2
  finish_h<<<1, 256, 0, stream>>>(part1, b1, W2, b2, h2);
  // K3: p, rd
  rop_kernel<<<1024, 256, 0, stream>>>((const float4*)Wro, bro,
                                       (const float4*)Wri, bri,
                                       (const float4*)Wp, bp, h2, pbuf, rdbuf);
  // K4: 10 value-iteration steps, one launch
  valiter_kernel<<<1024, 256, 0, stream>>>(pbuf, rdbuf, vbuf);
  // K5: Wpol v-column partials
  mv_polv<<<GRID_PV, 256, 0, stream>>>((const float4*)Wpol, (const float4*)vbuf,
                                       partPv);
  // K6: heads + softmax + state value
  finish_pol<<<1, 256, 0, stream>>>(partPx, partPv, bpol, Whead, bhead, vbuf,
                                    pos, out);
}

// Round 5
// 131.719 us; speedup vs baseline: 1.4467x; 1.4235x over previous
//
#include <hip/hip_runtime.h>

#define HW 512
#define NSTATE (HW * HW)   // 262144
#define NC4_X 196608       // x as float4 (3*H*W/4)
#define NC4_POLROW 262144  // Wpol row stride in float4
#define NC4_V 65536        // v as float4

// spans
#define SPAN_MV 3072   // float4 per wave-span in mv_dual (48 KB), 64 spans/row
#define NSPAN_MV 64
#define SPAN_PV 2048   // float4 per wave-span in mv_polv (32 KB), 32 spans/row
#define NSPAN_PV 32
#define SPAN_ROP 1024  // float4 per wave-span per matrix in rop (64 rows)

// ws layout (float offsets); 16B-aligned where needed
#define WS_PART1 0            // 64*32
#define WS_PARTPX 2048        // 64*32
#define WS_PARTPV 4096        // 32*32
#define WS_H2 5120            // 64
#define WS_P 5184             // 262144
#define WS_RD (WS_P + NSTATE)
#define WS_V (WS_RD + NSTATE)

#define SGB __builtin_amdgcn_sched_group_barrier

// ---------------------------------------------------------------------------
// K1: partials for W1@x and Wpol[:, x-cols]@x. ONE contiguous span per wave:
// wave = (matrix, span s of 64, rowgroup g, wave) -> row = 4g+wave.
// 2 contiguous streams (W row-span + x span). x spans are L2-hot (3 MB total,
// all spans resident simultaneously). R4 lesson: multi-row strided batches
// get serialized by the register allocator (VGPR pinned at 32).
// ---------------------------------------------------------------------------
__global__ __launch_bounds__(256) void mv_dual(
    const float4* __restrict__ W1, const float4* __restrict__ Wpol,
    const float4* __restrict__ x, float* __restrict__ part1,
    float* __restrict__ partPx) {
  int b = blockIdx.x;  // [0,1024)
  int m = b >> 9;
  int rest = b & 511;
  int s = rest >> 3;  // span 0..63
  int g = rest & 7;   // rowgroup
  int wave = threadIdx.x >> 6, lane = threadIdx.x & 63;
  int row = g * 4 + wave;  // 0..31
  const float4* __restrict__ Wrow =
      m ? (Wpol + (size_t)row * NC4_POLROW + NC4_V)
        : (W1 + (size_t)row * NC4_X);
  int c0 = s * SPAN_MV;
  const float4* __restrict__ wp = Wrow + c0 + lane;
  const float4* __restrict__ xp = x + c0 + lane;
  float a0 = 0.f, a1 = 0.f, a2 = 0.f, a3 = 0.f;
  for (int i = 0; i < SPAN_MV / 64; i += 4) {  // 48 iters, unroll 4
    float4 w0 = wp[(i + 0) * 64], x0 = xp[(i + 0) * 64];
    float4 w1 = wp[(i + 1) * 64], x1 = xp[(i + 1) * 64];
    float4 w2 = wp[(i + 2) * 64], x2 = xp[(i + 2) * 64];
    float4 w3 = wp[(i + 3) * 64], x3 = xp[(i + 3) * 64];
    a0 += w0.x * x0.x + w0.y * x0.y + w0.z * x0.z + w0.w * x0.w;
    a1 += w1.x * x1.x + w1.y * x1.y + w1.z * x1.z + w1.w * x1.w;
    a2 += w2.x * x2.x + w2.y * x2.y + w2.z * x2.z + w2.w * x2.w;
    a3 += w3.x * x3.x + w3.y * x3.y + w3.z * x3.z + w3.w * x3.w;
    SGB(0x020, 8, 0);  // 8 VMEM reads clustered
    SGB(0x002, 32, 0); // then VALU
  }
  float a = (a0 + a1) + (a2 + a3);
  a += __shfl_xor(a, 32);
  a += __shfl_xor(a, 16);
  a += __shfl_xor(a, 8);
  a += __shfl_xor(a, 4);
  a += __shfl_xor(a, 2);
  a += __shfl_xor(a, 1);
  if (lane == 0) {
    float* outp = m ? partPx : part1;
    outp[s * 32 + row] = a;
  }
}

// ---------------------------------------------------------------------------
// K5: partials for Wpol[:, v-cols] @ v. Same span structure (32 spans/row).
// ---------------------------------------------------------------------------
__global__ __launch_bounds__(256) void mv_polv(
    const float4* __restrict__ Wpol, const float4* __restrict__ v,
    float* __restrict__ partPv) {
  int b = blockIdx.x;  // [0,256)
  int s = b >> 3;      // span 0..31
  int g = b & 7;
  int wave = threadIdx.x >> 6, lane = threadIdx.x & 63;
  int row = g * 4 + wave;
  const float4* __restrict__ wp =
      Wpol + (size_t)row * NC4_POLROW + s * SPAN_PV + lane;
  const float4* __restrict__ vp = v + s * SPAN_PV + lane;
  float a0 = 0.f, a1 = 0.f, a2 = 0.f, a3 = 0.f;
  for (int i = 0; i < SPAN_PV / 64; i += 4) {  // 32 iters, unroll 4
    float4 w0 = wp[(i + 0) * 64], x0 = vp[(i + 0) * 64];
    float4 w1 = wp[(i + 1) * 64], x1 = vp[(i + 1) * 64];
    float4 w2 = wp[(i + 2) * 64], x2 = vp[(i + 2) * 64];
    float4 w3 = wp[(i + 3) * 64], x3 = vp[(i + 3) * 64];
    a0 += w0.x * x0.x + w0.y * x0.y + w0.z * x0.z + w0.w * x0.w;
    a1 += w1.x * x1.x + w1.y * x1.y + w1.z * x1.z + w1.w * x1.w;
    a2 += w2.x * x2.x + w2.y * x2.y + w2.z * x2.z + w2.w * x2.w;
    a3 += w3.x * x3.x + w3.y * x3.y + w3.z * x3.z + w3.w * x3.w;
    SGB(0x020, 8, 0);
    SGB(0x002, 32, 0);
  }
  float a = (a0 + a1) + (a2 + a3);
  a += __shfl_xor(a, 32);
  a += __shfl_xor(a, 16);
  a += __shfl_xor(a, 8);
  a += __shfl_xor(a, 4);
  a += __shfl_xor(a, 2);
  a += __shfl_xor(a, 1);
  if (lane == 0) partPv[s * 32 + row] = a;
}

// ---------------------------------------------------------------------------
// finish_h: reduce part1[64][32] -> h1 = relu(W1@x+b1); h2 = relu(W2@h1+b2).
// ---------------------------------------------------------------------------
__global__ __launch_bounds__(256) void finish_h(
    const float* __restrict__ partials, const float* __restrict__ b1,
    const float* __restrict__ W2, const float* __restrict__ b2,
    float* __restrict__ h2out) {
  __shared__ float red[8][32];
  __shared__ float h1[32];
  int tid = threadIdx.x;
  int row = tid & 31, grp = tid >> 5;
  float s = 0.f;
  for (int b = grp; b < NSPAN_MV; b += 8) s += partials[b * 32 + row];
  red[grp][row] = s;
  __syncthreads();
  if (tid < 32) {
    float t = b1[tid];
    for (int g = 0; g < 8; ++g) t += red[g][tid];
    h1[tid] = fmaxf(t, 0.f);
  }
  __syncthreads();
  if (tid < 64) {
    float t = b2[tid];
    for (int k = 0; k < 32; ++k) t += W2[tid * 32 + k] * h1[k];
    h2out[tid] = fmaxf(t, 0.f);
  }
}

// ---------------------------------------------------------------------------
// rop: p = sig(Wp@h2+bp), rd = sig(Wri@h2+bri) - sig(Wro@h2+bro).
// Flat-span streaming: matrix = 4,194,304 float4; wave span = 1024 float4
// (64 rows), contiguous. k4 = lane&15 is constant per lane; every wave-load
// completes 4 rows via 16-lane groups. 2 batches of 8 independent loads +
// 8 independent reduce chains per matrix. 1024 blocks, 256 rows/block.
// ---------------------------------------------------------------------------
__global__ __launch_bounds__(256) void rop_kernel(
    const float4* __restrict__ Wro4, const float* __restrict__ bro,
    const float4* __restrict__ Wri4, const float* __restrict__ bri,
    const float4* __restrict__ Wp4, const float* __restrict__ bp,
    const float* __restrict__ h2, float* __restrict__ p_out,
    float* __restrict__ rd_out) {
  __shared__ float dots[4][3][64];
  int tid = threadIdx.x;
  int wave = tid >> 6, lane = tid & 63;
  int grp = lane >> 4;
  float4 h4 = ((const float4*)h2)[lane & 15];
  int span = blockIdx.x * 4 + wave;         // [0,4096)
  size_t base = (size_t)span * SPAN_ROP;    // first float4 of span
  const float4* mats[3] = {Wro4, Wri4, Wp4};
#pragma unroll
  for (int m = 0; m < 3; ++m) {
    const float4* __restrict__ W = mats[m] + base + lane;
#pragma unroll
    for (int batch = 0; batch < 2; ++batch) {
      float4 w[8];
#pragma unroll
      for (int j = 0; j < 8; ++j) w[j] = W[(batch * 8 + j) * 64];
      SGB(0x020, 8, 0);  // keep the 8-load cluster
      float part[8];
#pragma unroll
      for (int j = 0; j < 8; ++j)
        part[j] = w[j].x * h4.x + w[j].y * h4.y + w[j].z * h4.z + w[j].w * h4.w;
#pragma unroll
      for (int j = 0; j < 8; ++j) {
        part[j] += __shfl_xor(part[j], 8);
        part[j] += __shfl_xor(part[j], 4);
        part[j] += __shfl_xor(part[j], 2);
        part[j] += __shfl_xor(part[j], 1);
      }
      if ((lane & 15) == 0) {
#pragma unroll
        for (int j = 0; j < 8; ++j)
          dots[wave][m][(batch * 8 + j) * 4 + grp] = part[j];
      }
    }
  }
  __syncthreads();
  int o = blockIdx.x * 256 + tid;
  float dro = dots[tid >> 6][0][tid & 63] + bro[o];
  float dri = dots[tid >> 6][1][tid & 63] + bri[o];
  float dp = dots[tid >> 6][2][tid & 63] + bp[o];
  float sro = 1.f / (1.f + __expf(-dro));
  float sri = 1.f / (1.f + __expf(-dri));
  float pv = 1.f / (1.f + __expf(-dp));
  p_out[o] = pv;
  rd_out[o] = sri - sro;
}

// ---------------------------------------------------------------------------
// Value iteration, ONE launch, 1024 blocks. 16x16 tile + halo 10 in LDS,
// 10 local iterations; zero-padding semantics preserved.
// ---------------------------------------------------------------------------
#define TILE 16
#define HALO 10
#define LR 36  // TILE + 2*HALO
__global__ __launch_bounds__(256) void valiter_kernel(
    const float* __restrict__ p, const float* __restrict__ rd,
    float* __restrict__ vout) {
  __shared__ float u[LR + 2][LR + 3];
  __shared__ float pp[LR][LR + 1];
  __shared__ float rr[LR][LR + 1];
  __shared__ float vv[LR][LR + 1];
  int tid = threadIdx.x;
  int ti = blockIdx.x >> 5, tj = blockIdx.x & 31;
  int gi0 = ti * TILE - HALO, gj0 = tj * TILE - HALO;
  for (int idx = tid; idx < (LR + 2) * (LR + 3); idx += 256)
    ((float*)u)[idx] = 0.f;
  for (int idx = tid; idx < LR * LR; idx += 256) {
    int i = idx / LR, j = idx % LR;
    int gi = gi0 + i, gj = gj0 + j;
    bool ok = (gi >= 0) & (gi < HW) & (gj >= 0) & (gj < HW);
    pp[i][j] = ok ? p[gi * HW + gj] : 0.f;
    rr[i][j] = ok ? rd[gi * HW + gj] : 0.f;
    vv[i][j] = 0.f;
  }
  __syncthreads();
  for (int k = 0; k < 10; ++k) {
#pragma unroll
    for (int idx = tid; idx < LR * LR; idx += 256) {
      int i = idx / LR, j = idx % LR;
      u[i + 1][j + 1] = vv[i][j] * pp[i][j] + rr[i][j];
    }
    __syncthreads();
#pragma unroll
    for (int idx = tid; idx < LR * LR; idx += 256) {
      int i = idx / LR, j = idx % LR;
      float m = u[i][j];
      m = fmaxf(m, u[i][j + 1]);
      m = fmaxf(m, u[i][j + 2]);
      m = fmaxf(m, u[i + 1][j]);
      m = fmaxf(m, u[i + 1][j + 2]);
      m = fmaxf(m, u[i + 2][j]);
      m = fmaxf(m, u[i + 2][j + 1]);
      m = fmaxf(m, u[i + 2][j + 2]);
      vv[i][j] = m;
    }
    __syncthreads();
  }
  if (tid < TILE * TILE) {
    int a = tid >> 4, b = tid & 15;
    vout[(ti * TILE + a) * HW + tj * TILE + b] = vv[HALO + a][HALO + b];
  }
}

// ---------------------------------------------------------------------------
// finish_pol: hp = relu(bpol + sum partPx[64][32] + sum partPv[32][32]);
// logits = Whead@hp + bhead; softmax; out[8] = v[pos].
// ---------------------------------------------------------------------------
__global__ __launch_bounds__(256) void finish_pol(
    const float* __restrict__ partPx, const float* __restrict__ partPv,
    const float* __restrict__ bpol, const float* __restrict__ Whead,
    const float* __restrict__ bhead, const float* __restrict__ v,
    const int* __restrict__ pos, float* __restrict__ out) {
  __shared__ float red[8][32];
  __shared__ float hp[32];
  __shared__ float logits[8];
  int tid = threadIdx.x;
  int row = tid & 31, grp = tid >> 5;
  float s = 0.f;
  for (int b = grp; b < NSPAN_MV; b += 8) s += partPx[b * 32 + row];
  for (int b = grp; b < NSPAN_PV; b += 8) s += partPv[b * 32 + row];
  red[grp][row] = s;
  __syncthreads();
  if (tid < 32) {
    float t = bpol[tid];
    for (int g = 0; g < 8; ++g) t += red[g][tid];
    hp[tid] = fmaxf(t, 0.f);
  }
  __syncthreads();
  if (tid < 8) {
    float t = bhead[tid];
    for (int k = 0; k < 32; ++k) t += Whead[tid * 32 + k] * hp[k];
    logits[tid] = t;
  }
  __syncthreads();
  if (tid == 0) {
    float mx = logits[0];
    for (int j = 1; j < 8; ++j) mx = fmaxf(mx, logits[j]);
    float e[8], sum = 0.f;
    for (int j = 0; j < 8; ++j) {
      e[j] = __expf(logits[j] - mx);
      sum += e[j];
    }
    for (int j = 0; j < 8; ++j) out[j] = e[j] / sum;
    out[8] = v[pos[0] * HW + pos[1]];
  }
}

extern "C" void kernel_launch(void* const* d_in, const int* in_sizes, int n_in,
                              void* d_out, int out_size, void* d_ws,
                              size_t ws_size, hipStream_t stream) {
  const float* x = (const float*)d_in[0];
  const int* pos = (const int*)d_in[1];
  const float* W1 = (const float*)d_in[2];
  const float* b1 = (const float*)d_in[3];
  const float* W2 = (const float*)d_in[4];
  const float* b2 = (const float*)d_in[5];
  const float* Wro = (const float*)d_in[6];
  const float* bro = (const float*)d_in[7];
  const float* Wri = (const float*)d_in[8];
  const float* bri = (const float*)d_in[9];
  const float* Wp = (const float*)d_in[10];
  const float* bp = (const float*)d_in[11];
  const float* Wpol = (const float*)d_in[12];
  const float* bpol = (const float*)d_in[13];
  const float* Whead = (const float*)d_in[14];
  const float* bhead = (const float*)d_in[15];
  float* ws = (float*)d_ws;
  float* out = (float*)d_out;

  float* part1 = ws + WS_PART1;
  float* partPx = ws + WS_PARTPX;
  float* partPv = ws + WS_PARTPV;
  float* h2 = ws + WS_H2;
  float* pbuf = ws + WS_P;
  float* rdbuf = ws + WS_RD;
  float* vbuf = ws + WS_V;

  // K1: W1@x partials AND Wpol x-column partials (independent of v)
  mv_dual<<<1024, 256, 0, stream>>>((const float4*)W1, (const float4*)Wpol,
                                    (const float4*)x, part1, partPx);
  // K2: h1 -> h2
  finish_h<<<1, 256, 0, stream>>>(part1, b1, W2, b2, h2);
  // K3: p, rd
  rop_kernel<<<1024, 256, 0, stream>>>((const float4*)Wro, bro,
                                       (const float4*)Wri, bri,
                                       (const float4*)Wp, bp, h2, pbuf, rdbuf);
  // K4: 10 value-iteration steps, one launch
  valiter_kernel<<<1024, 256, 0, stream>>>(pbuf, rdbuf, vbuf);
  // K5: Wpol v-column partials
  mv_polv<<<256, 256, 0, stream>>>((const float4*)Wpol, (const float4*)vbuf,
                                   partPv);
  // K6: heads + softmax + state value
  finish_pol<<<1, 256, 0, stream>>>(partPx, partPv, bpol, Whead, bhead, vbuf,
                                    pos, out);
}

// Round 6
// 131.232 us; speedup vs baseline: 1.4521x; 1.0037x over previous
//
#include <hip/hip_runtime.h>

#define HW 512
#define NSTATE (HW * HW)   // 262144
#define NC4_X 196608       // x as float4 (3*H*W/4)
#define NC4_POLROW 262144  // Wpol row stride in float4
#define NC4_V 65536        // v as float4

#define SPAN_MV 3072  // float4 per wave-span in mv_dual (48 KB), 64 spans/row
#define NSPAN_MV 64
#define CHUNK4 128                     // float4 per W chunk (2 KB)
#define NCHUNK_MV (SPAN_MV / CHUNK4)   // 24
#define SPAN_PV 2048                   // float4 per wave-span in mv_polv
#define NSPAN_PV 32
#define NCHUNK_PV (SPAN_PV / CHUNK4)   // 16
#define SPAN_ROP 1024

// ws layout (float offsets)
#define WS_PART1 0
#define WS_PARTPX 2048
#define WS_PARTPV 4096
#define WS_H2 5120
#define WS_P 5184
#define WS_RD (WS_P + NSTATE)
#define WS_V (WS_RD + NSTATE)

#define SGB __builtin_amdgcn_sched_group_barrier

// Async global->LDS, 16B per lane, dest = wave-uniform base + lane*16.
__device__ __forceinline__ void gl_lds16(const float4* g, float4* l) {
  __builtin_amdgcn_global_load_lds(
      (const __attribute__((address_space(1))) void*)g,
      (__attribute__((address_space(3))) void*)l, 16, 0, 0);
}
__device__ __forceinline__ float dot4(float4 a, float4 b) {
  return a.x * b.x + a.y * b.y + a.z * b.z + a.w * b.w;
}

// ---------------------------------------------------------------------------
// K1: partials for W1@x and Wpol[:, x-cols]@x. R3-R5 lesson: VGPR-targeted
// load batches get serialized by the register allocator (VGPR pinned 20-32,
// 1.3 TB/s). Fix: global_load_lds — loads bypass VGPRs entirely.
// Block = (m, span s, rowgroup g); 4 waves = 4 rows; shared 48 KB x-span
// staged once into LDS; per-wave W double-buffer (2 KB chunks) with counted
// vmcnt(2), no in-loop barriers (each wave owns its buffer).
// ---------------------------------------------------------------------------
__global__ __launch_bounds__(256) void mv_dual(
    const float4* __restrict__ W1, const float4* __restrict__ Wpol,
    const float4* __restrict__ x, float* __restrict__ part1,
    float* __restrict__ partPx) {
  __shared__ float4 xs[SPAN_MV];       // 48 KB
  __shared__ float4 wb[4][2][CHUNK4];  // 16 KB
  int b = blockIdx.x;  // [0,1024)
  int m = b >> 9, rest = b & 511, s = rest >> 3, g = rest & 7;
  int tid = threadIdx.x, wave = tid >> 6, lane = tid & 63;
  int row = g * 4 + wave;  // 0..31
  const float4* __restrict__ wp =
      (m ? (Wpol + (size_t)row * NC4_POLROW + NC4_V)
         : (W1 + (size_t)row * NC4_X)) +
      (size_t)s * SPAN_MV;
  const float4* __restrict__ xp = x + (size_t)s * SPAN_MV;
  // cooperative x-span stage: 12 x 1KB per wave, zero VGPR cost
  for (int j = 0; j < 12; ++j) {
    int blk = wave * 12 + j;
    gl_lds16(xp + blk * 64 + lane, &xs[blk * 64]);
  }
  // prologue: W chunk 0
  gl_lds16(wp + lane, &wb[wave][0][0]);
  gl_lds16(wp + 64 + lane, &wb[wave][0][64]);
  __syncthreads();  // one-time drain: x + chunk0 resident
  float acc0 = 0.f, acc1 = 0.f;
  int buf = 0;
  for (int i = 0; i < NCHUNK_MV; ++i) {
    if (i + 1 < NCHUNK_MV) {
      gl_lds16(wp + (i + 1) * CHUNK4 + lane, &wb[wave][buf ^ 1][0]);
      gl_lds16(wp + (i + 1) * CHUNK4 + 64 + lane, &wb[wave][buf ^ 1][64]);
      asm volatile("s_waitcnt vmcnt(2)" ::: "memory");  // chunk i ready
    } else {
      asm volatile("s_waitcnt vmcnt(0)" ::: "memory");
    }
    __builtin_amdgcn_sched_barrier(0);
    float4 w0 = wb[wave][buf][lane];
    float4 w1 = wb[wave][buf][64 + lane];
    float4 x0 = xs[i * CHUNK4 + lane];
    float4 x1 = xs[i * CHUNK4 + 64 + lane];
    acc0 += dot4(w0, x0);
    acc1 += dot4(w1, x1);
    buf ^= 1;
  }
  float a = acc0 + acc1;
  a += __shfl_xor(a, 32);
  a += __shfl_xor(a, 16);
  a += __shfl_xor(a, 8);
  a += __shfl_xor(a, 4);
  a += __shfl_xor(a, 2);
  a += __shfl_xor(a, 1);
  if (lane == 0) (m ? partPx : part1)[s * 32 + row] = a;
}

// ---------------------------------------------------------------------------
// K5: partials for Wpol[:, v-cols] @ v. Same global_load_lds template.
// ---------------------------------------------------------------------------
__global__ __launch_bounds__(256) void mv_polv(
    const float4* __restrict__ Wpol, const float4* __restrict__ v,
    float* __restrict__ partPv) {
  __shared__ float4 xs[SPAN_PV];       // 32 KB
  __shared__ float4 wb[4][2][CHUNK4];  // 16 KB
  int b = blockIdx.x;  // [0,256)
  int s = b >> 3, g = b & 7;
  int tid = threadIdx.x, wave = tid >> 6, lane = tid & 63;
  int row = g * 4 + wave;
  const float4* __restrict__ wp =
      Wpol + (size_t)row * NC4_POLROW + (size_t)s * SPAN_PV;
  const float4* __restrict__ vp = v + (size_t)s * SPAN_PV;
  for (int j = 0; j < 8; ++j) {  // 8 x 1KB per wave
    int blk = wave * 8 + j;
    gl_lds16(vp + blk * 64 + lane, &xs[blk * 64]);
  }
  gl_lds16(wp + lane, &wb[wave][0][0]);
  gl_lds16(wp + 64 + lane, &wb[wave][0][64]);
  __syncthreads();
  float acc0 = 0.f, acc1 = 0.f;
  int buf = 0;
  for (int i = 0; i < NCHUNK_PV; ++i) {
    if (i + 1 < NCHUNK_PV) {
      gl_lds16(wp + (i + 1) * CHUNK4 + lane, &wb[wave][buf ^ 1][0]);
      gl_lds16(wp + (i + 1) * CHUNK4 + 64 + lane, &wb[wave][buf ^ 1][64]);
      asm volatile("s_waitcnt vmcnt(2)" ::: "memory");
    } else {
      asm volatile("s_waitcnt vmcnt(0)" ::: "memory");
    }
    __builtin_amdgcn_sched_barrier(0);
    float4 w0 = wb[wave][buf][lane];
    float4 w1 = wb[wave][buf][64 + lane];
    float4 x0 = xs[i * CHUNK4 + lane];
    float4 x1 = xs[i * CHUNK4 + 64 + lane];
    acc0 += dot4(w0, x0);
    acc1 += dot4(w1, x1);
    buf ^= 1;
  }
  float a = acc0 + acc1;
  a += __shfl_xor(a, 32);
  a += __shfl_xor(a, 16);
  a += __shfl_xor(a, 8);
  a += __shfl_xor(a, 4);
  a += __shfl_xor(a, 2);
  a += __shfl_xor(a, 1);
  if (lane == 0) partPv[s * 32 + row] = a;
}

// ---------------------------------------------------------------------------
// finish_h: reduce part1[64][32] -> h1 = relu(W1@x+b1); h2 = relu(W2@h1+b2).
// ---------------------------------------------------------------------------
__global__ __launch_bounds__(256) void finish_h(
    const float* __restrict__ partials, const float* __restrict__ b1,
    const float* __restrict__ W2, const float* __restrict__ b2,
    float* __restrict__ h2out) {
  __shared__ float red[8][32];
  __shared__ float h1[32];
  int tid = threadIdx.x;
  int row = tid & 31, grp = tid >> 5;
  float s = 0.f;
  for (int b = grp; b < NSPAN_MV; b += 8) s += partials[b * 32 + row];
  red[grp][row] = s;
  __syncthreads();
  if (tid < 32) {
    float t = b1[tid];
    for (int g = 0; g < 8; ++g) t += red[g][tid];
    h1[tid] = fmaxf(t, 0.f);
  }
  __syncthreads();
  if (tid < 64) {
    float t = b2[tid];
    for (int k = 0; k < 32; ++k) t += W2[tid * 32 + k] * h1[k];
    h2out[tid] = fmaxf(t, 0.f);
  }
}

// ---------------------------------------------------------------------------
// rop: p = sig(Wp@h2+bp), rd = sig(Wri@h2+bri) - sig(Wro@h2+bro).
// Flat-span streaming (R5 version, improved then — unchanged).
// ---------------------------------------------------------------------------
__global__ __launch_bounds__(256) void rop_kernel(
    const float4* __restrict__ Wro4, const float* __restrict__ bro,
    const float4* __restrict__ Wri4, const float* __restrict__ bri,
    const float4* __restrict__ Wp4, const float* __restrict__ bp,
    const float* __restrict__ h2, float* __restrict__ p_out,
    float* __restrict__ rd_out) {
  __shared__ float dots[4][3][64];
  int tid = threadIdx.x;
  int wave = tid >> 6, lane = tid & 63;
  int grp = lane >> 4;
  float4 h4 = ((const float4*)h2)[lane & 15];
  int span = blockIdx.x * 4 + wave;       // [0,4096)
  size_t base = (size_t)span * SPAN_ROP;  // first float4 of span
  const float4* mats[3] = {Wro4, Wri4, Wp4};
#pragma unroll
  for (int m = 0; m < 3; ++m) {
    const float4* __restrict__ W = mats[m] + base + lane;
#pragma unroll
    for (int batch = 0; batch < 2; ++batch) {
      float4 w[8];
#pragma unroll
      for (int j = 0; j < 8; ++j) w[j] = W[(batch * 8 + j) * 64];
      SGB(0x020, 8, 0);
      float part[8];
#pragma unroll
      for (int j = 0; j < 8; ++j)
        part[j] = w[j].x * h4.x + w[j].y * h4.y + w[j].z * h4.z + w[j].w * h4.w;
#pragma unroll
      for (int j = 0; j < 8; ++j) {
        part[j] += __shfl_xor(part[j], 8);
        part[j] += __shfl_xor(part[j], 4);
        part[j] += __shfl_xor(part[j], 2);
        part[j] += __shfl_xor(part[j], 1);
      }
      if ((lane & 15) == 0) {
#pragma unroll
        for (int j = 0; j < 8; ++j)
          dots[wave][m][(batch * 8 + j) * 4 + grp] = part[j];
      }
    }
  }
  __syncthreads();
  int o = blockIdx.x * 256 + tid;
  float dro = dots[tid >> 6][0][tid & 63] + bro[o];
  float dri = dots[tid >> 6][1][tid & 63] + bri[o];
  float dp = dots[tid >> 6][2][tid & 63] + bp[o];
  float sro = 1.f / (1.f + __expf(-dro));
  float sri = 1.f / (1.f + __expf(-dri));
  float pv = 1.f / (1.f + __expf(-dp));
  p_out[o] = pv;
  rd_out[o] = sri - sro;
}

// ---------------------------------------------------------------------------
// Value iteration, ONE launch, 1024 blocks. 16x16 tile + halo 10 in LDS,
// 10 local iterations; zero-padding semantics preserved.
// ---------------------------------------------------------------------------
#define TILE 16
#define HALO 10
#define LR 36  // TILE + 2*HALO
__global__ __launch_bounds__(256) void valiter_kernel(
    const float* __restrict__ p, const float* __restrict__ rd,
    float* __restrict__ vout) {
  __shared__ float u[LR + 2][LR + 3];
  __shared__ float pp[LR][LR + 1];
  __shared__ float rr[LR][LR + 1];
  __shared__ float vv[LR][LR + 1];
  int tid = threadIdx.x;
  int ti = blockIdx.x >> 5, tj = blockIdx.x & 31;
  int gi0 = ti * TILE - HALO, gj0 = tj * TILE - HALO;
  for (int idx = tid; idx < (LR + 2) * (LR + 3); idx += 256)
    ((float*)u)[idx] = 0.f;
  for (int idx = tid; idx < LR * LR; idx += 256) {
    int i = idx / LR, j = idx % LR;
    int gi = gi0 + i, gj = gj0 + j;
    bool ok = (gi >= 0) & (gi < HW) & (gj >= 0) & (gj < HW);
    pp[i][j] = ok ? p[gi * HW + gj] : 0.f;
    rr[i][j] = ok ? rd[gi * HW + gj] : 0.f;
    vv[i][j] = 0.f;
  }
  __syncthreads();
  for (int k = 0; k < 10; ++k) {
#pragma unroll
    for (int idx = tid; idx < LR * LR; idx += 256) {
      int i = idx / LR, j = idx % LR;
      u[i + 1][j + 1] = vv[i][j] * pp[i][j] + rr[i][j];
    }
    __syncthreads();
#pragma unroll
    for (int idx = tid; idx < LR * LR; idx += 256) {
      int i = idx / LR, j = idx % LR;
      float m = u[i][j];
      m = fmaxf(m, u[i][j + 1]);
      m = fmaxf(m, u[i][j + 2]);
      m = fmaxf(m, u[i + 1][j]);
      m = fmaxf(m, u[i + 1][j + 2]);
      m = fmaxf(m, u[i + 2][j]);
      m = fmaxf(m, u[i + 2][j + 1]);
      m = fmaxf(m, u[i + 2][j + 2]);
      vv[i][j] = m;
    }
    __syncthreads();
  }
  if (tid < TILE * TILE) {
    int a = tid >> 4, b = tid & 15;
    vout[(ti * TILE + a) * HW + tj * TILE + b] = vv[HALO + a][HALO + b];
  }
}

// ---------------------------------------------------------------------------
// finish_pol: hp = relu(bpol + sum partPx[64][32] + sum partPv[32][32]);
// logits = Whead@hp + bhead; softmax; out[8] = v[pos].
// ---------------------------------------------------------------------------
__global__ __launch_bounds__(256) void finish_pol(
    const float* __restrict__ partPx, const float* __restrict__ partPv,
    const float* __restrict__ bpol, const float* __restrict__ Whead,
    const float* __restrict__ bhead, const float* __restrict__ v,
    const int* __restrict__ pos, float* __restrict__ out) {
  __shared__ float red[8][32];
  __shared__ float hp[32];
  __shared__ float logits[8];
  int tid = threadIdx.x;
  int row = tid & 31, grp = tid >> 5;
  float s = 0.f;
  for (int b = grp; b < NSPAN_MV; b += 8) s += partPx[b * 32 + row];
  for (int b = grp; b < NSPAN_PV; b += 8) s += partPv[b * 32 + row];
  red[grp][row] = s;
  __syncthreads();
  if (tid < 32) {
    float t = bpol[tid];
    for (int g = 0; g < 8; ++g) t += red[g][tid];
    hp[tid] = fmaxf(t, 0.f);
  }
  __syncthreads();
  if (tid < 8) {
    float t = bhead[tid];
    for (int k = 0; k < 32; ++k) t += Whead[tid * 32 + k] * hp[k];
    logits[tid] = t;
  }
  __syncthreads();
  if (tid == 0) {
    float mx = logits[0];
    for (int j = 1; j < 8; ++j) mx = fmaxf(mx, logits[j]);
    float e[8], sum = 0.f;
    for (int j = 0; j < 8; ++j) {
      e[j] = __expf(logits[j] - mx);
      sum += e[j];
    }
    for (int j = 0; j < 8; ++j) out[j] = e[j] / sum;
    out[8] = v[pos[0] * HW + pos[1]];
  }
}

extern "C" void kernel_launch(void* const* d_in, const int* in_sizes, int n_in,
                              void* d_out, int out_size, void* d_ws,
                              size_t ws_size, hipStream_t stream) {
  const float* x = (const float*)d_in[0];
  const int* pos = (const int*)d_in[1];
  const float* W1 = (const float*)d_in[2];
  const float* b1 = (const float*)d_in[3];
  const float* W2 = (const float*)d_in[4];
  const float* b2 = (const float*)d_in[5];
  const float* Wro = (const float*)d_in[6];
  const float* bro = (const float*)d_in[7];
  const float* Wri = (const float*)d_in[8];
  const float* bri = (const float*)d_in[9];
  const float* Wp = (const float*)d_in[10];
  const float* bp = (const float*)d_in[11];
  const float* Wpol = (const float*)d_in[12];
  const float* bpol = (const float*)d_in[13];
  const float* Whead = (const float*)d_in[14];
  const float* bhead = (const float*)d_in[15];
  float* ws = (float*)d_ws;
  float* out = (float*)d_out;

  float* part1 = ws + WS_PART1;
  float* partPx = ws + WS_PARTPX;
  float* partPv = ws + WS_PARTPV;
  float* h2 = ws + WS_H2;
  float* pbuf = ws + WS_P;
  float* rdbuf = ws + WS_RD;
  float* vbuf = ws + WS_V;

  // K1: W1@x partials AND Wpol x-column partials (independent of v)
  mv_dual<<<1024, 256, 0, stream>>>((const float4*)W1, (const float4*)Wpol,
                                    (const float4*)x, part1, partPx);
  // K2: h1 -> h2
  finish_h<<<1, 256, 0, stream>>>(part1, b1, W2, b2, h2);
  // K3: p, rd
  rop_kernel<<<1024, 256, 0, stream>>>((const float4*)Wro, bro,
                                       (const float4*)Wri, bri,
                                       (const float4*)Wp, bp, h2, pbuf, rdbuf);
  // K4: 10 value-iteration steps, one launch
  valiter_kernel<<<1024, 256, 0, stream>>>(pbuf, rdbuf, vbuf);
  // K5: Wpol v-column partials
  mv_polv<<<256, 256, 0, stream>>>((const float4*)Wpol, (const float4*)vbuf,
                                   partPv);
  // K6: heads + softmax + state value
  finish_pol<<<1, 256, 0, stream>>>(partPx, partPv, bpol, Whead, bhead, vbuf,
                                    pos, out);
}